// Round 6
// baseline (2350.494 us; speedup 1.0000x reference)
//
#include <hip/hip_runtime.h>
#include <math.h>

#define NPTS 4096
#define DIM  64
#define MAX_ITERS 36

#define ALOG (-8.317766166719343f)   /* -log(4096) */
#define L2E  (1.4426950408889634f)
#define LN2  (0.6931471805599453f)

#if __has_builtin(__builtin_amdgcn_exp2f)
#define EXP2F(x) __builtin_amdgcn_exp2f(x)
#else
#define EXP2F(x) exp2f(x)
#endif
#if __has_builtin(__builtin_amdgcn_logf)
#define LOG2F(x) __builtin_amdgcn_logf(x)
#else
#define LOG2F(x) log2f(x)
#endif

typedef _Float16 f16x8 __attribute__((ext_vector_type(8)));
typedef float    f32x4 __attribute__((ext_vector_type(4)));

/* ---------------- min/max partial reduction (per-dim, both x and y) ------ */
__global__ void minmax_part_kernel(const float* __restrict__ x,
                                   const float* __restrict__ y,
                                   float* __restrict__ partmn,
                                   float* __restrict__ partmx) {
    int t = threadIdx.x;
    int bid = blockIdx.x;               // 128 blocks
    int g0 = bid * 256 + t;
    const int total = NPTS * DIM;
    float mn = INFINITY, mx = -INFINITY;
    for (int g = g0; g < total; g += 128 * 256) {
        float v = x[g]; mn = fminf(mn, v); mx = fmaxf(mx, v);
        float w = y[g]; mn = fminf(mn, w); mx = fmaxf(mx, w);
    }
    __shared__ float smn[256], smx[256];
    smn[t] = mn; smx[t] = mx;
    __syncthreads();
    if (t < 64) {
        for (int q = 1; q < 4; q++) {
            mn = fminf(mn, smn[t + 64 * q]);
            mx = fmaxf(mx, smx[t + 64 * q]);
        }
        partmn[bid * 64 + t] = mn;
        partmx[bid * 64 + t] = mx;
    }
}

/* ---------------- eps schedule (replicates numpy in f64) ----------------- */
__global__ void schedule_kernel(const float* __restrict__ partmn,
                                const float* __restrict__ partmx,
                                int* __restrict__ hdr,
                                float* __restrict__ sched) {
    int d = threadIdx.x;  // 64 threads
    float mn = INFINITY, mx = -INFINITY;
    for (int b = 0; b < 128; b++) {
        mn = fminf(mn, partmn[b * 64 + d]);
        mx = fmaxf(mx, partmx[b * 64 + d]);
    }
    float range = mx - mn;
    __shared__ float r2[64];
    r2[d] = range * range;
    __syncthreads();
    if (d == 0) {
        float ss = 0.f;
        for (int k = 0; k < 64; k++) ss += r2[k];
        float diam_f = sqrtf(ss);
        double diam = (double)diam_f;
        double start = 2.0 * log(diam);
        double stop  = 2.0 * log(0.05);
        double step  = 2.0 * log(0.8);
        int n_ar = (int)ceil((stop - start) / step);
        if (n_ar < 0) n_ar = 0;
        int n_eps = n_ar + 2;
        if (n_eps > 64) n_eps = 64;
        sched[0] = (float)(diam * diam);
        for (int k = 0; k < n_ar && (1 + k) < 63; k++)
            sched[1 + k] = (float)exp(start + step * (double)k);
        sched[n_eps - 1] = 0.0025f;
        for (int k = n_eps; k < 64; k++) sched[k] = 0.0025f;
        hdr[0] = n_eps;
    }
}

/* ---------------- squared norms (wave per row, from f32 inputs) ---------- */
__global__ void sqnorm_kernel(const float* __restrict__ X, float* __restrict__ out) {
    int wave = (blockIdx.x * blockDim.x + threadIdx.x) >> 6;
    int lane = threadIdx.x & 63;
    if (wave >= NPTS) return;
    float v = X[wave * DIM + lane];
    float s = v * v;
    for (int o = 32; o > 0; o >>= 1) s += __shfl_xor(s, o, 64);
    if (lane == 0) out[wave] = s;
}

/* ---------------- cast f32 -> f16 for MFMA inputs ------------------------ */
__global__ void cast_kernel(const float* __restrict__ x, const float* __restrict__ y,
                            _Float16* __restrict__ X16, _Float16* __restrict__ Y16) {
    int g = blockIdx.x * 256 + threadIdx.x;
    X16[g] = (_Float16)x[g];
    Y16[g] = (_Float16)y[g];
}

/* ---------------- h2 init: zero potentials, eps = sched[0] --------------- */
__global__ void hinit_kernel(const float* __restrict__ x2, const float* __restrict__ y2,
                             const float* __restrict__ sched,
                             float* __restrict__ hxy, float* __restrict__ hyx,
                             float* __restrict__ hxx, float* __restrict__ hyy) {
    int j = blockIdx.x * 256 + threadIdx.x;
    float inv20 = L2E / sched[0];
    float b = ALOG * L2E;
    float hx = b - 0.5f * x2[j] * inv20;
    float hy = b - 0.5f * y2[j] * inv20;
    hxy[j] = hy;   /* softmin over rows of Sxy sums over y-columns */
    hyx[j] = hx;
    hxx[j] = hx;
    hyy[j] = hy;
}

/* ---------------- fused MFMA scores + row-LSE pass ----------------------- */
/* grid: 4 mats x 64 rowblocks x 4 colsplits = 1024 blocks, 256 thr         */
struct PassArgs {
    const _Float16* Am[4];     /* A-side points (rows) */
    const _Float16* Bm[4];     /* B-side points (cols), row-major = B^T      */
    const float* h2in[4];      /* per-direction column-h (log2 domain)       */
    float* Pm; float* Ps;      /* partials [mat][cs][4096]                   */
    const int* hdr; const float* sched;
    int t;
};

__global__ __launch_bounds__(256) void pass_kernel(PassArgs A) {
    int n_eps = A.hdr[0];
    if (A.t >= 0 && A.t >= n_eps) return;      /* padded iteration */
    int idx = (A.t == -2) ? 0 : ((A.t == -1) ? n_eps - 1 : A.t);
    float inv2 = L2E / A.sched[idx];

    int b = blockIdx.x;
    int mat = b >> 8, rb = (b >> 2) & 63, cs = b & 3;
    const _Float16* Amat = A.Am[mat];
    const _Float16* Bmat = A.Bm[mat] + (size_t)(cs * 1024) * DIM;
    const float* h2v = A.h2in[mat] + cs * 1024;

    __shared__ float hs[1024];
    int tt = threadIdx.x;
    *(float4*)&hs[tt * 4] = *(const float4*)&h2v[tt * 4];
    __syncthreads();

    int wave = tt >> 6, lane = tt & 63;
    int quad = lane >> 4, lo = lane & 15;
    int row0 = rb * 64 + wave * 16;

    const _Float16* arow = Amat + (size_t)(row0 + lo) * DIM + quad * 8;
    f16x8 a0 = *(const f16x8*)(arow);
    f16x8 a1 = *(const f16x8*)(arow + 32);

    float m[4] = {-INFINITY, -INFINITY, -INFINITY, -INFINITY};
    float s[4] = {0.f, 0.f, 0.f, 0.f};

    for (int sb = 0; sb < 16; sb++) {
        float v[4][4];
#pragma unroll
        for (int cc = 0; cc < 4; cc++) {
            int cb = sb * 64 + cc * 16;
            const _Float16* brow = Bmat + (size_t)(cb + lo) * DIM + quad * 8;
            f16x8 b0 = *(const f16x8*)(brow);
            f16x8 b1 = *(const f16x8*)(brow + 32);
            f32x4 acc = {0.f, 0.f, 0.f, 0.f};
            acc = __builtin_amdgcn_mfma_f32_16x16x32_f16(a0, b0, acc, 0, 0, 0);
            acc = __builtin_amdgcn_mfma_f32_16x16x32_f16(a1, b1, acc, 0, 0, 0);
            float hval = hs[cb + lo];
#pragma unroll
            for (int r = 0; r < 4; r++) v[r][cc] = fmaf(acc[r], inv2, hval);
        }
#pragma unroll
        for (int r = 0; r < 4; r++) {
            float lm = fmaxf(fmaxf(v[r][0], v[r][1]), fmaxf(v[r][2], v[r][3]));
            if (lm > m[r] - 26.0f) {           /* exp elision for cold strips */
                float nm = fmaxf(m[r], lm);
                float acc = s[r] * EXP2F(m[r] - nm);
                acc += EXP2F(v[r][0] - nm) + EXP2F(v[r][1] - nm)
                     + EXP2F(v[r][2] - nm) + EXP2F(v[r][3] - nm);
                m[r] = nm; s[r] = acc;
            }
        }
    }
    /* merge across the 16 low lanes (cols) sharing each row */
#pragma unroll
    for (int off = 1; off < 16; off <<= 1) {
#pragma unroll
        for (int r = 0; r < 4; r++) {
            float om = __shfl_xor(m[r], off, 64);
            float os = __shfl_xor(s[r], off, 64);
            float nm = fmaxf(m[r], om);
            s[r] = s[r] * EXP2F(m[r] - nm) + os * EXP2F(om - nm);
            m[r] = nm;
        }
    }
    if (lo == 0) {
#pragma unroll
        for (int r = 0; r < 4; r++) {
            int row = row0 + quad * 4 + r;
            int pi = (mat * 4 + cs) * NPTS + row;
            A.Pm[pi] = m[r]; A.Ps[pi] = s[r];
        }
    }
}

/* ---------------- combine 4 col-split partials, chain f/h2 --------------- */
struct CombArgs {
    const float* Pm; const float* Ps;
    const float* sq[4];
    const float* fold[4]; float* fout[4];
    float* h2out[4];               /* coupled-direction next-h buffer */
    const float* h2cp[4];          /* coupled-direction current h (pad copy) */
    const int* hdr; const float* sched;
    int t;
};

__global__ void comb_kernel(CombArgs A) {
    int g = blockIdx.x * 256 + threadIdx.x;     /* 16384 */
    int mat = g >> 12, row = g & 4095;
    int n_eps = A.hdr[0];
    if (A.t >= 0 && A.t >= n_eps) {             /* padded iteration: copy */
        A.fout[mat][row] = A.fold[mat][row];
        A.h2out[mat][row] = A.h2cp[mat][row];
        return;
    }
    int idx  = (A.t == -2) ? 0 : ((A.t == -1) ? n_eps - 1 : A.t);
    int nidx = (A.t == -2) ? 0 : ((A.t == -1) ? n_eps - 1 : min(A.t + 1, n_eps - 1));
    float eps = A.sched[idx];
    float inv2n = L2E / A.sched[nidx];
    float M = -INFINITY;
#pragma unroll
    for (int q = 0; q < 4; q++) M = fmaxf(M, A.Pm[(mat * 4 + q) * NPTS + row]);
    float S = 0.f;
#pragma unroll
    for (int q = 0; q < 4; q++)
        S += A.Ps[(mat * 4 + q) * NPTS + row] * EXP2F(A.Pm[(mat * 4 + q) * NPTS + row] - M);
    float sq = A.sq[mat][row];
    float res = 0.5f * sq - eps * LN2 * (M + LOG2F(S));
    float fnew = (A.t >= 0) ? 0.5f * (A.fold[mat][row] + res) : res;
    A.fout[mat][row] = fnew;
    A.h2out[mat][row] = ALOG * L2E + (fnew - 0.5f * sq) * inv2n;
}

/* ---------------- final reduction: mean(fba-faa)+mean(gab-gbb) ----------- */
__global__ void reduce_kernel(const float* __restrict__ fba, const float* __restrict__ faa,
                              const float* __restrict__ gab, const float* __restrict__ gbb,
                              float* __restrict__ out) {
    int t = threadIdx.x;
    double s1 = 0.0, s2 = 0.0;
    for (int i = t; i < NPTS; i += 256) {
        s1 += (double)fba[i] - (double)faa[i];
        s2 += (double)gab[i] - (double)gbb[i];
    }
    __shared__ double sh1[256], sh2[256];
    sh1[t] = s1; sh2[t] = s2;
    __syncthreads();
    for (int o = 128; o > 0; o >>= 1) {
        if (t < o) { sh1[t] += sh1[t + o]; sh2[t] += sh2[t + o]; }
        __syncthreads();
    }
    if (t == 0) out[0] = (float)(sh1[0] / NPTS + sh2[0] / NPTS);
}

extern "C" void kernel_launch(void* const* d_in, const int* in_sizes, int n_in,
                              void* d_out, int out_size, void* d_ws, size_t ws_size,
                              hipStream_t stream) {
    const float* x = (const float*)d_in[0];
    const float* y = (const float*)d_in[1];
    float* out = (float*)d_out;
    float* w = (float*)d_ws;

    int*   hdr   = (int*)w;                 /* 16 */
    float* sched = w + 16;                  /* 64 */
    float* pmn   = w + 80;                  /* 8192 */
    float* pmx   = w + 8272;                /* 8192 */
    float* x2    = w + 16464;               /* 4096 */
    float* y2    = w + 20560;               /* 4096 */
    float* fb    = w + 24656;               /* 8*4096 f[mat][ping] */
    float* hb    = w + 57424;               /* 8*4096 h2[mat][ping] */
    auto F  = [&](int mat, int p) { return fb + (mat * 2 + p) * 4096; };
    auto H2 = [&](int mat, int p) { return hb + (mat * 2 + p) * 4096; };
    float* Pm = w + 90192;                  /* 4*4*4096 */
    float* Ps = w + 155728;                 /* 4*4*4096 */
    _Float16* X16 = (_Float16*)(w + 221264);   /* 262144 halves */
    _Float16* Y16 = (_Float16*)(w + 352336);
    const int couple[4] = {1, 0, 2, 3};

    /* setup */
    hipLaunchKernelGGL(minmax_part_kernel, dim3(128), dim3(256), 0, stream, x, y, pmn, pmx);
    hipLaunchKernelGGL(schedule_kernel, dim3(1), dim3(64), 0, stream, pmn, pmx, hdr, sched);
    hipLaunchKernelGGL(sqnorm_kernel, dim3(1024), dim3(256), 0, stream, x, x2);
    hipLaunchKernelGGL(sqnorm_kernel, dim3(1024), dim3(256), 0, stream, y, y2);
    hipLaunchKernelGGL(cast_kernel, dim3(1024), dim3(256), 0, stream, x, y, X16, Y16);
    hipLaunchKernelGGL(hinit_kernel, dim3(16), dim3(256), 0, stream,
                       x2, y2, sched, H2(0, 0), H2(1, 0), H2(2, 0), H2(3, 0));

    PassArgs PA;
    PA.Am[0] = X16; PA.Bm[0] = Y16;   /* xy */
    PA.Am[1] = Y16; PA.Bm[1] = X16;   /* yx */
    PA.Am[2] = X16; PA.Bm[2] = X16;   /* xx */
    PA.Am[3] = Y16; PA.Bm[3] = Y16;   /* yy */
    PA.Pm = Pm; PA.Ps = Ps; PA.hdr = hdr; PA.sched = sched;

    CombArgs CA;
    CA.Pm = Pm; CA.Ps = Ps;
    CA.sq[0] = x2; CA.sq[1] = y2; CA.sq[2] = x2; CA.sq[3] = y2;
    CA.hdr = hdr; CA.sched = sched;

    /* init phase (t=-2): reads h2[.][0]; writes f[.][0], h2[couple][1] */
    for (int m = 0; m < 4; m++) PA.h2in[m] = H2(m, 0);
    PA.t = -2;
    hipLaunchKernelGGL(pass_kernel, dim3(1024), dim3(256), 0, stream, PA);
    for (int m = 0; m < 4; m++) {
        CA.fold[m] = F(m, 1); CA.fout[m] = F(m, 0);
        CA.h2out[m] = H2(couple[m], 1); CA.h2cp[m] = H2(couple[m], 0);
    }
    CA.t = -2;
    hipLaunchKernelGGL(comb_kernel, dim3(64), dim3(256), 0, stream, CA);

    /* annealing loop: iter t reads f[pf], h2[1-pf]; writes f[1-pf], h2[pf] */
    for (int t = 0; t < MAX_ITERS; t++) {
        int pf = t & 1;
        for (int m = 0; m < 4; m++) PA.h2in[m] = H2(m, 1 - pf);
        PA.t = t;
        hipLaunchKernelGGL(pass_kernel, dim3(1024), dim3(256), 0, stream, PA);
        for (int m = 0; m < 4; m++) {
            CA.fold[m] = F(m, pf); CA.fout[m] = F(m, 1 - pf);
            CA.h2out[m] = H2(couple[m], pf); CA.h2cp[m] = H2(couple[m], 1 - pf);
        }
        CA.t = t;
        hipLaunchKernelGGL(comb_kernel, dim3(64), dim3(256), 0, stream, CA);
    }

    /* final extrapolation (t=-1): reads h2[.][1], f[.][0]; writes f[.][1] */
    for (int m = 0; m < 4; m++) PA.h2in[m] = H2(m, 1);
    PA.t = -1;
    hipLaunchKernelGGL(pass_kernel, dim3(1024), dim3(256), 0, stream, PA);
    for (int m = 0; m < 4; m++) {
        CA.fold[m] = F(m, 0); CA.fout[m] = F(m, 1);
        CA.h2out[m] = H2(couple[m], 0); CA.h2cp[m] = H2(couple[m], 1);
    }
    CA.t = -1;
    hipLaunchKernelGGL(comb_kernel, dim3(64), dim3(256), 0, stream, CA);

    hipLaunchKernelGGL(reduce_kernel, dim3(1), dim3(256), 0, stream,
                       F(0, 1), F(2, 1), F(1, 1), F(3, 1), out);
}

// Round 7
// 981.173 us; speedup vs baseline: 2.3956x; 2.3956x over previous
//
#include <hip/hip_runtime.h>
#include <math.h>

#define NPTS 4096
#define DIM  64
#define MAX_ITERS 37        /* pass indices 0..36 cover n_eps <= 36 */

#define ALOG (-8.317766166719343f)   /* -log(4096) */
#define L2E  (1.4426950408889634f)
#define LN2  (0.6931471805599453f)

#if __has_builtin(__builtin_amdgcn_exp2f)
#define EXP2F(x) __builtin_amdgcn_exp2f(x)
#else
#define EXP2F(x) exp2f(x)
#endif
#if __has_builtin(__builtin_amdgcn_logf)
#define LOG2F(x) __builtin_amdgcn_logf(x)
#else
#define LOG2F(x) log2f(x)
#endif

typedef _Float16 f16x8 __attribute__((ext_vector_type(8)));
typedef float    f32x4 __attribute__((ext_vector_type(4)));

/* ---------------- min/max partial reduction (per-dim, both x and y) ------ */
__global__ void minmax_part_kernel(const float* __restrict__ x,
                                   const float* __restrict__ y,
                                   float* __restrict__ partmn,
                                   float* __restrict__ partmx) {
    int t = threadIdx.x;
    int bid = blockIdx.x;               // 128 blocks
    int g0 = bid * 256 + t;
    const int total = NPTS * DIM;
    float mn = INFINITY, mx = -INFINITY;
    for (int g = g0; g < total; g += 128 * 256) {
        float v = x[g]; mn = fminf(mn, v); mx = fmaxf(mx, v);
        float w = y[g]; mn = fminf(mn, w); mx = fmaxf(mx, w);
    }
    __shared__ float smn[256], smx[256];
    smn[t] = mn; smx[t] = mx;
    __syncthreads();
    if (t < 64) {
        for (int q = 1; q < 4; q++) {
            mn = fminf(mn, smn[t + 64 * q]);
            mx = fmaxf(mx, smx[t + 64 * q]);
        }
        partmn[bid * 64 + t] = mn;
        partmx[bid * 64 + t] = mx;
    }
}

/* ---------------- eps schedule (replicates numpy in f64) ----------------- */
__global__ void schedule_kernel(const float* __restrict__ partmn,
                                const float* __restrict__ partmx,
                                int* __restrict__ hdr,
                                float* __restrict__ sched) {
    int d = threadIdx.x;  // 64 threads
    float mn = INFINITY, mx = -INFINITY;
    for (int b = 0; b < 128; b++) {
        mn = fminf(mn, partmn[b * 64 + d]);
        mx = fmaxf(mx, partmx[b * 64 + d]);
    }
    float range = mx - mn;
    __shared__ float r2[64];
    r2[d] = range * range;
    __syncthreads();
    if (d == 0) {
        float ss = 0.f;
        for (int k = 0; k < 64; k++) ss += r2[k];
        float diam_f = sqrtf(ss);
        double diam = (double)diam_f;
        double start = 2.0 * log(diam);
        double stop  = 2.0 * log(0.05);
        double step  = 2.0 * log(0.8);
        int n_ar = (int)ceil((stop - start) / step);
        if (n_ar < 0) n_ar = 0;
        int n_eps = n_ar + 2;
        if (n_eps > 63) n_eps = 63;
        sched[0] = (float)(diam * diam);
        for (int k = 0; k < n_ar && (1 + k) < 63; k++)
            sched[1 + k] = (float)exp(start + step * (double)k);
        sched[n_eps - 1] = 0.0025f;
        for (int k = n_eps; k < 64; k++) sched[k] = 0.0025f;
        hdr[0] = n_eps;
    }
}

/* ---------------- squared norms (wave per row, from f32 inputs) ---------- */
__global__ void sqnorm_kernel(const float* __restrict__ X, float* __restrict__ out) {
    int wave = (blockIdx.x * blockDim.x + threadIdx.x) >> 6;
    int lane = threadIdx.x & 63;
    if (wave >= NPTS) return;
    float v = X[wave * DIM + lane];
    float s = v * v;
    for (int o = 32; o > 0; o >>= 1) s += __shfl_xor(s, o, 64);
    if (lane == 0) out[wave] = s;
}

/* ---------------- cast f32 -> f16 for MFMA inputs ------------------------ */
__global__ void cast_kernel(const float* __restrict__ x, const float* __restrict__ y,
                            _Float16* __restrict__ X16, _Float16* __restrict__ Y16) {
    int g = blockIdx.x * 256 + threadIdx.x;
    X16[g] = (_Float16)x[g];
    Y16[g] = (_Float16)y[g];
}

/* =======================================================================
   Fused pass: prologue recombines previous iteration's partials into this
   pass's h-vector (per block, redundantly); main computes MFMA scores +
   row-LSE partials for this iteration.
   grid: 1024 = mat(4) x rowblock(32 of 128 rows) x colsplit(8 of 512 cols)
   P layout: P + ping*262144; Pm then Ps (131072 each); index (mat*8+cs)*4096+row
   F layout: F + ping*16384 + mat*4096 + row ; H: H + mat*4096 + col
   Partial pings: init(t=-2) writes 1; pass t>=0 writes t&1; final writes n_eps&1.
   ======================================================================= */
__global__ __launch_bounds__(256, 4) void pass_kernel(
        const _Float16* __restrict__ X16, const _Float16* __restrict__ Y16,
        const float* __restrict__ x2, const float* __restrict__ y2,
        float* __restrict__ F, float* __restrict__ H, float* __restrict__ P,
        const int* __restrict__ hdr, const float* __restrict__ sched, int t) {
    const int n_eps = hdr[0];
    if (t >= 0 && t > n_eps) return;           /* fully padded pass */

    int b = blockIdx.x;
    int mat = b >> 8, rb = (b >> 3) & 31, cs = b & 7;
    const _Float16* Am = (mat == 0 || mat == 2) ? X16 : Y16;
    const _Float16* Bm = (mat == 1 || mat == 2) ? X16 : Y16;
    int matc = (mat < 2) ? (1 - mat) : mat;                 /* coupled mat */
    const float* sqr = (mat == 0 || mat == 2) ? x2 : y2;    /* row norms  */
    const float* sqc = (matc == 0 || matc == 2) ? x2 : y2;  /* col norms  */

    __shared__ float hs[512];
    __shared__ _Float16 Bs[2][64][72];

    int tt = threadIdx.x;
    int c0 = cs * 512, r0 = rb * 128;

    /* ---------------- prologue: build hs ---------------- */
    if (t == -2) {
        float inv2i = L2E / sched[0];
        for (int r = tt; r < 512; r += 256)
            hs[r] = ALOG * L2E - 0.5f * sqc[c0 + r] * inv2i;
    } else if (t == -1) {
        for (int r = tt; r < 512; r += 256)
            hs[r] = H[mat * 4096 + c0 + r];
    } else {
        /* comb of prev = t-1 (init partials if t==0) */
        int pp = (t == 0) ? 1 : ((t - 1) & 1);
        const float* Pm = P + pp * 262144;
        const float* Ps = Pm + 131072;
        float epsp = sched[(t == 0) ? 0 : (t - 1)];
        float inv2c = L2E / sched[t];       /* t<=36<64, sched padded */
        for (int r = tt; r < 512; r += 256) {
            int row = c0 + r;
            int base = (matc * 8) * NPTS + row;
            float M = -INFINITY;
#pragma unroll
            for (int q = 0; q < 8; q++) M = fmaxf(M, Pm[base + q * NPTS]);
            float S = 0.f;
#pragma unroll
            for (int q = 0; q < 8; q++)
                S += Ps[base + q * NPTS] * EXP2F(Pm[base + q * NPTS] - M);
            float sq = sqc[row];
            float res = 0.5f * sq - epsp * LN2 * (M + LOG2F(S));
            float fnew = (t == 0) ? res
                       : 0.5f * (F[((t - 1) & 1) * 16384 + matc * 4096 + row] + res);
            float h = ALOG * L2E + (fnew - 0.5f * sq) * inv2c;
            hs[r] = h;
            if (rb == 0) {
                F[(t & 1) * 16384 + matc * 4096 + row] = fnew;
                H[mat * 4096 + row] = h;
            }
        }
    }
    __syncthreads();
    if (t >= 0 && t >= n_eps) return;          /* prologue-only pass (t==n_eps) */

    /* ---------------- main: MFMA scores + row-LSE ---------------- */
    int idx = (t == -2) ? 0 : ((t == -1) ? n_eps - 1 : t);
    float inv2 = L2E / sched[idx];

    int wv = tt >> 6, lane = tt & 63, q = lane >> 4, lo = lane & 15;

    f16x8 a[2][2];
#pragma unroll
    for (int rt = 0; rt < 2; rt++) {
        const _Float16* ar = Am + (size_t)(r0 + wv * 32 + rt * 16 + lo) * DIM + q * 8;
        a[rt][0] = *(const f16x8*)ar;
        a[rt][1] = *(const f16x8*)(ar + 32);
    }

    int srow = tt >> 2, scol = (tt & 3) * 16;
    {
        const _Float16* src = Bm + (size_t)(c0 + srow) * DIM + scol;
        *(f16x8*)&Bs[0][srow][scol]     = *(const f16x8*)src;
        *(f16x8*)&Bs[0][srow][scol + 8] = *(const f16x8*)(src + 8);
    }

    float m[2][4], s[2][4];
#pragma unroll
    for (int rt = 0; rt < 2; rt++)
#pragma unroll
        for (int r = 0; r < 4; r++) { m[rt][r] = -INFINITY; s[rt][r] = 0.f; }

    for (int ct = 0; ct < 8; ct++) {
        __syncthreads();
        f16x8 n0, n1;
        if (ct < 7) {
            const _Float16* src = Bm + (size_t)(c0 + (ct + 1) * 64 + srow) * DIM + scol;
            n0 = *(const f16x8*)src;
            n1 = *(const f16x8*)(src + 8);
        }
        const _Float16 (*Bt)[72] = Bs[ct & 1];
        float v[2][4][4];
#pragma unroll
        for (int cc = 0; cc < 4; cc++) {
            const _Float16* br = &Bt[cc * 16 + lo][q * 8];
            f16x8 b0 = *(const f16x8*)br;
            f16x8 b1 = *(const f16x8*)(br + 32);
            float hval = hs[ct * 64 + cc * 16 + lo];
#pragma unroll
            for (int rt = 0; rt < 2; rt++) {
                f32x4 acc = {0.f, 0.f, 0.f, 0.f};
                acc = __builtin_amdgcn_mfma_f32_16x16x32_f16(a[rt][0], b0, acc, 0, 0, 0);
                acc = __builtin_amdgcn_mfma_f32_16x16x32_f16(a[rt][1], b1, acc, 0, 0, 0);
#pragma unroll
                for (int r = 0; r < 4; r++) v[rt][r][cc] = fmaf(acc[r], inv2, hval);
            }
        }
#pragma unroll
        for (int rt = 0; rt < 2; rt++)
#pragma unroll
            for (int r = 0; r < 4; r++) {
                float lm = fmaxf(fmaxf(v[rt][r][0], v[rt][r][1]),
                                 fmaxf(v[rt][r][2], v[rt][r][3]));
                if (lm > m[rt][r] - 26.0f) {   /* exp elision for cold strips */
                    float nm = fmaxf(m[rt][r], lm);
                    float acc = s[rt][r] * EXP2F(m[rt][r] - nm);
                    acc += EXP2F(v[rt][r][0] - nm) + EXP2F(v[rt][r][1] - nm)
                         + EXP2F(v[rt][r][2] - nm) + EXP2F(v[rt][r][3] - nm);
                    m[rt][r] = nm; s[rt][r] = acc;
                }
            }
        if (ct < 7) {
            *(f16x8*)&Bs[(ct + 1) & 1][srow][scol]     = n0;
            *(f16x8*)&Bs[(ct + 1) & 1][srow][scol + 8] = n1;
        }
    }

    /* merge across the 16 low-lanes (cols) sharing each row */
#pragma unroll
    for (int off = 1; off < 16; off <<= 1) {
#pragma unroll
        for (int rt = 0; rt < 2; rt++)
#pragma unroll
            for (int r = 0; r < 4; r++) {
                float om = __shfl_xor(m[rt][r], off, 64);
                float os = __shfl_xor(s[rt][r], off, 64);
                float nm = fmaxf(m[rt][r], om);
                s[rt][r] = s[rt][r] * EXP2F(m[rt][r] - nm) + os * EXP2F(om - nm);
                m[rt][r] = nm;
            }
    }
    if (lo == 0) {
        int pw = (t == -1) ? (n_eps & 1) : ((t == -2) ? 1 : (t & 1));
        float* Pm = P + pw * 262144;
        float* Ps = Pm + 131072;
#pragma unroll
        for (int rt = 0; rt < 2; rt++)
#pragma unroll
            for (int r = 0; r < 4; r++) {
                int row = r0 + wv * 32 + rt * 16 + q * 4 + r;
                Pm[(mat * 8 + cs) * NPTS + row] = m[rt][r];
                Ps[(mat * 8 + cs) * NPTS + row] = s[rt][r];
            }
    }
}

/* ---------------- finalize: comb of final partials + signed mean --------- */
__global__ void finalize_kernel(const float* __restrict__ P,
                                const float* __restrict__ x2, const float* __restrict__ y2,
                                const int* __restrict__ hdr, const float* __restrict__ sched,
                                float* __restrict__ out) {
    int n_eps = hdr[0];
    const float* Pm = P + (n_eps & 1) * 262144;
    const float* Ps = Pm + 131072;
    int g = blockIdx.x * 256 + threadIdx.x;    /* 64 blocks x 256 = 16384 */
    int mat = g >> 12, row = g & 4095;
    float eps = sched[n_eps - 1];
    const float* sqr = (mat == 0 || mat == 2) ? x2 : y2;
    int base = (mat * 8) * NPTS + row;
    float M = -INFINITY;
#pragma unroll
    for (int q = 0; q < 8; q++) M = fmaxf(M, Pm[base + q * NPTS]);
    float S = 0.f;
#pragma unroll
    for (int q = 0; q < 8; q++) S += Ps[base + q * NPTS] * EXP2F(Pm[base + q * NPTS] - M);
    float res = 0.5f * sqr[row] - eps * LN2 * (M + LOG2F(S));
    float val = ((mat == 0 || mat == 1) ? res : -res) * (1.0f / NPTS);
    __shared__ float sh[256];
    sh[threadIdx.x] = val;
    __syncthreads();
    for (int o = 128; o > 0; o >>= 1) {
        if (threadIdx.x < o) sh[threadIdx.x] += sh[threadIdx.x + o];
        __syncthreads();
    }
    if (threadIdx.x == 0) atomicAdd(out, sh[0]);
}

extern "C" void kernel_launch(void* const* d_in, const int* in_sizes, int n_in,
                              void* d_out, int out_size, void* d_ws, size_t ws_size,
                              hipStream_t stream) {
    const float* x = (const float*)d_in[0];
    const float* y = (const float*)d_in[1];
    float* out = (float*)d_out;
    float* w = (float*)d_ws;

    int*   hdr   = (int*)w;                 /* 16 */
    float* sched = w + 16;                  /* 64 */
    float* pmn   = w + 80;                  /* 8192 */
    float* pmx   = w + 8272;                /* 8192 */
    float* x2    = w + 16464;               /* 4096 */
    float* y2    = w + 20560;               /* 4096 */
    float* F     = w + 24656;               /* 2*4*4096 = 32768 */
    float* H     = w + 57424;               /* 4*4096 = 16384 */
    float* P     = w + 73808;               /* 2*2*131072 = 524288 */
    _Float16* X16 = (_Float16*)(w + 598096);   /* 262144 halves */
    _Float16* Y16 = (_Float16*)(w + 729168);

    hipMemsetAsync(out, 0, sizeof(float), stream);

    /* setup */
    hipLaunchKernelGGL(minmax_part_kernel, dim3(128), dim3(256), 0, stream, x, y, pmn, pmx);
    hipLaunchKernelGGL(schedule_kernel, dim3(1), dim3(64), 0, stream, pmn, pmx, hdr, sched);
    hipLaunchKernelGGL(sqnorm_kernel, dim3(1024), dim3(256), 0, stream, x, x2);
    hipLaunchKernelGGL(sqnorm_kernel, dim3(1024), dim3(256), 0, stream, y, y2);
    hipLaunchKernelGGL(cast_kernel, dim3(1024), dim3(256), 0, stream, x, y, X16, Y16);

    /* init pass (t=-2), annealing passes, final pass */
    hipLaunchKernelGGL(pass_kernel, dim3(1024), dim3(256), 0, stream,
                       X16, Y16, x2, y2, F, H, P, hdr, sched, -2);
    for (int t = 0; t < MAX_ITERS; t++)
        hipLaunchKernelGGL(pass_kernel, dim3(1024), dim3(256), 0, stream,
                           X16, Y16, x2, y2, F, H, P, hdr, sched, t);
    hipLaunchKernelGGL(pass_kernel, dim3(1024), dim3(256), 0, stream,
                       X16, Y16, x2, y2, F, H, P, hdr, sched, -1);

    hipLaunchKernelGGL(finalize_kernel, dim3(64), dim3(256), 0, stream,
                       P, x2, y2, hdr, sched, out);
}